// Round 10
// baseline (374.660 us; speedup 1.0000x reference)
//
#include <hip/hip_runtime.h>
#include <cstdint>

// Problem constants (from reference): B=8192, DIN=DOUT=4096, NC=64
#define BB   8192
#define DIN  4096
#define DOUT 4096
#define NCL  64

typedef __bf16 bf16;
typedef __attribute__((ext_vector_type(8)))  __bf16 bf16x8;
typedef __attribute__((ext_vector_type(4)))  float  f32x4;
typedef __attribute__((ext_vector_type(16))) float  f32x16;

#define GAS(p) (reinterpret_cast<uint32_t __attribute__((address_space(1)))*>(reinterpret_cast<uintptr_t>(p)))
#define LAS(p) (reinterpret_cast<uint32_t __attribute__((address_space(3)))*>(reinterpret_cast<uintptr_t>(p)))

#define WAITV(n)  asm volatile("s_waitcnt vmcnt(" #n ")" ::: "memory")
#define WAITL()   asm volatile("s_waitcnt lgkmcnt(0)" ::: "memory")
#define BARR()    __builtin_amdgcn_s_barrier()
#define SCHED0()  __builtin_amdgcn_sched_barrier(0)
#define MFMA16(a, b, c) __builtin_amdgcn_mfma_f32_16x16x32_bf16((a), (b), (c), 0, 0, 0)
#define MFMA32(a, b, c) __builtin_amdgcn_mfma_f32_32x32x16_bf16((a), (b), (c), 0, 0, 0)

// ---------------------------------------------------------------------------
// Kernel 1: prologue (R7-proven, unchanged). tmpL = cluster @ style_L (K=64
// MFMA); A' = bf16(x*tmpL) via LDS bounce (coalesced x/Ap streams).
// blockIdx.y==0 blocks also dump the cluster tile as bf16 for the GEMM.
// ---------------------------------------------------------------------------
__global__ __launch_bounds__(256) void prologue_kernel(
    const float* __restrict__ x, const float* __restrict__ cl,
    const float* __restrict__ sL, bf16* __restrict__ Ap,
    bf16* __restrict__ clb)
{
    __shared__ char lds[34816];
    const int t    = threadIdx.x;
    const int lane = t & 63;
    const int w    = t >> 6;
    const int wm   = w >> 1, wn = w & 1;
    const int r0   = blockIdx.x * 128;
    const int c0   = blockIdx.y * 128;

    #pragma unroll
    for (int i = 0; i < 4; i++) {
        int tk  = t + i * 256;
        int row = tk >> 3, ch = tk & 7;
        const float* src = cl + (size_t)(r0 + row) * NCL + ch * 8;
        float4 v0 = *(const float4*)src;
        float4 v1 = *(const float4*)(src + 4);
        bf16x8 pk;
        pk[0]=(bf16)v0.x; pk[1]=(bf16)v0.y; pk[2]=(bf16)v0.z; pk[3]=(bf16)v0.w;
        pk[4]=(bf16)v1.x; pk[5]=(bf16)v1.y; pk[6]=(bf16)v1.z; pk[7]=(bf16)v1.w;
        *(bf16x8*)(lds + row * 128 + ((ch ^ (row & 7)) << 4)) = pk;
        if (blockIdx.y == 0)
            *(bf16x8*)(clb + (size_t)(r0 + row) * NCL + ch * 8) = pk;
    }
    #pragma unroll
    for (int i = 0; i < 4; i++) {
        int tk = t + i * 256;
        int n  = tk & 127, c = tk >> 7;
        bf16x8 pl;
        #pragma unroll
        for (int j = 0; j < 8; j++)
            pl[j] = (bf16)sL[(size_t)(c * 8 + j) * DIN + c0 + n];
        *(bf16x8*)(lds + 16384 + n * 128 + ((c ^ (n & 7)) << 4)) = pl;
    }
    __syncthreads();

    f32x4 accL[4][4] = {};
    #pragma unroll
    for (int s = 0; s < 2; s++) {
        bf16x8 a[4], bl[4];
        #pragma unroll
        for (int m = 0; m < 4; m++) {
            int row = wm * 64 + m * 16 + (lane & 15);
            int ch  = s * 4 + (lane >> 4);
            a[m] = *(bf16x8*)(lds + row * 128 + ((ch ^ (row & 7)) << 4));
        }
        #pragma unroll
        for (int n = 0; n < 4; n++) {
            int row = wn * 64 + n * 16 + (lane & 15);
            int ch  = s * 4 + (lane >> 4);
            bl[n] = *(bf16x8*)(lds + 16384 + row * 128 + ((ch ^ (row & 7)) << 4));
        }
        #pragma unroll
        for (int m = 0; m < 4; m++)
            #pragma unroll
            for (int n = 0; n < 4; n++)
                accL[m][n] = MFMA16(a[m], bl[n], accL[m][n]);
    }
    __syncthreads();

    #pragma unroll
    for (int m = 0; m < 4; m++) {
        int rbase = wm * 64 + m * 16 + ((lane >> 4) << 2);
        #pragma unroll
        for (int n = 0; n < 4; n++) {
            int col = wn * 64 + n * 16 + (lane & 15);
            #pragma unroll
            for (int j = 0; j < 4; j++)
                *(bf16*)(lds + (rbase + j) * 272 + col * 2) = (bf16)accL[m][n][j];
        }
    }
    __syncthreads();

    const int L = t & 15, H = (t >> 4) & 3;
    #pragma unroll
    for (int it = 0; it < 8; it++) {
        int row = it * 16 + w * 4 + H;
        bf16x8 tl = *(const bf16x8*)(lds + row * 272 + L * 16);
        const float* xs = x + (size_t)(r0 + row) * DIN + c0 + L * 8;
        float4 x0 = *(const float4*)xs;
        float4 x1 = *(const float4*)(xs + 4);
        bf16x8 o;
        o[0]=(bf16)(x0.x*(float)tl[0]); o[1]=(bf16)(x0.y*(float)tl[1]);
        o[2]=(bf16)(x0.z*(float)tl[2]); o[3]=(bf16)(x0.w*(float)tl[3]);
        o[4]=(bf16)(x1.x*(float)tl[4]); o[5]=(bf16)(x1.y*(float)tl[5]);
        o[6]=(bf16)(x1.z*(float)tl[6]); o[7]=(bf16)(x1.w*(float)tl[7]);
        *(bf16x8*)(Ap + (size_t)(r0 + row) * DIN + c0 + L * 8) = o;
    }
}

// ---------------------------------------------------------------------------
// Kernel 2 (fused streaming prep, unchanged):
//   blocks [0,2048):    W (DIN x DOUT f32) -> Wt (DOUT x DIN bf16)
//   blocks [2048,2064): style_R (64 x DOUT f32) -> sRt (DOUT x 64 bf16)
// ---------------------------------------------------------------------------
__global__ __launch_bounds__(256) void wprep_kernel(
    const float* __restrict__ W, const float* __restrict__ sR,
    bf16* __restrict__ Wt, bf16* __restrict__ srt)
{
    const int bid = blockIdx.x;
    const int t   = threadIdx.x;
    if (bid < 2048) {
        const int n  = (bid & 15) * 256 + t;
        const int k0 = (bid >> 4) * 32;
        bf16x8 v[4];
        #pragma unroll
        for (int q = 0; q < 4; q++)
            #pragma unroll
            for (int j = 0; j < 8; j++)
                v[q][j] = (bf16)W[(size_t)(k0 + q * 8 + j) * DOUT + n];
        bf16* dst = Wt + (size_t)n * DIN + k0;
        #pragma unroll
        for (int q = 0; q < 4; q++)
            *(bf16x8*)(dst + q * 8) = v[q];
    } else {
        const int o = (bid - 2048) * 256 + t;
        bf16x8 v[8];
        #pragma unroll
        for (int q = 0; q < 8; q++)
            #pragma unroll
            for (int j = 0; j < 8; j++)
                v[q][j] = (bf16)sR[(size_t)(q * 8 + j) * DOUT + o];
        bf16* dst = srt + (size_t)o * 64;
        #pragma unroll
        for (int q = 0; q < 8; q++)
            *(bf16x8*)(dst + q * 8) = v[q];
    }
}

// ---------------------------------------------------------------------------
// Kernel 3: 256x256 GEMM on v_mfma_f32_32x32x16_bf16, CHUNK-MAJOR LDS layout
// (conflict-free 32-row fragment reads), R9's 4-barrier schedule.
//
// LDS: 2 buf x {Ah0@0, Ah1@16K, Bh0@32K, Bh1@48K}; each 16KB piece = two 8KB
// sub-calls (64 rows each) laid out chunk-major: off = chunk*1024 + row*16.
// Staging thread tid loads global (row=tid&63, chunk=tid>>6) -> dest tid*16.
// Frag read (lane l, kk): chunk = kk*2 + (l>>5), row = base + (l&31) ->
// two contiguous 512B blocks per wave = zero bank conflicts.
// Waves 2M x 4N; per-wave 128 rows x 64 cols = 4 m-frags x 2 n-frags of 32x32.
// Phases/tile (CB = buf[t&1]; stage slots + vmcnt(6) identical to R9):
//   P1: ds aL(8)+b0(4); stage (t+1).Ah1->OB; BAR; lgkm0; 8 MFMA aL*b0; sched0
//   P2: ds b1(4);       stage (t+2).Bh0->CB; BAR; lgkm0; 8 MFMA aL*b1; sched0
//   P3: ds aH(8);       stage (t+2).Bh1->CB; BAR; lgkm0; 8 MFMA aH*b1; sched0
//   P4: (no reads)      stage (t+2).Ah0->CB; vmcnt(6); BAR; 8 MFMA aH*b0
// Slot-death: Ah0 read P1 / staged P4; Bh0 read P1 / staged P2 (1 full MFMA
// cluster margin); Bh1 read P2 / staged P3; Ah1 read P3 / staged next P1.
// A/B frag layout (R6-verified): row|col = l&31, k = (l>>5)*8 + j.
// C/D (m74/m101): col = l&31, row = (reg&3) + 8*(reg>>2) + 4*(l>>5).
// ---------------------------------------------------------------------------
template<int CUR>
__device__ __forceinline__ void tile_step(char* lds, int tid,
    const bf16* pA1, const bf16* pA2, const bf16* pA3, const bf16* pA4,
    const bf16* pB1, const bf16* pB2, const bf16* pB3, const bf16* pB4,
    int kA1, int kA2, int abase, int bbase,
    int ks0, int ks1, int ks2, int ks3,
    bf16x8 (&a)[2][4], bf16x8 (&b0)[4], bf16x8 (&b1)[4], f32x16 (&acc)[4][2])
{
    constexpr int CB = CUR * 65536;
    constexpr int OB = (CUR ^ 1) * 65536;
    const int ks[4] = {ks0, ks1, ks2, ks3};

    // ---------- P1 ----------
    #pragma unroll
    for (int mf = 0; mf < 2; ++mf)
        #pragma unroll
        for (int kk = 0; kk < 4; ++kk)
            a[mf][kk] = *(const bf16x8*)(lds + CB + abase + mf * 512 + ks[kk]);
    #pragma unroll
    for (int kk = 0; kk < 4; ++kk)
        b0[kk] = *(const bf16x8*)(lds + CB + bbase + ks[kk]);
    __builtin_amdgcn_global_load_lds(GAS(pA3 + kA1), LAS(lds + OB + 16384 + tid * 16), 16, 0, 0);
    __builtin_amdgcn_global_load_lds(GAS(pA4 + kA1), LAS(lds + OB + 24576 + tid * 16), 16, 0, 0);
    BARR();
    WAITL(); SCHED0();
    __builtin_amdgcn_s_setprio(1);
    #pragma unroll
    for (int kk = 0; kk < 4; ++kk)
        #pragma unroll
        for (int mf = 0; mf < 2; ++mf)
            acc[mf][0] = MFMA32(a[mf][kk], b0[kk], acc[mf][0]);
    __builtin_amdgcn_s_setprio(0);
    SCHED0();

    // ---------- P2 ----------
    #pragma unroll
    for (int kk = 0; kk < 4; ++kk)
        b1[kk] = *(const bf16x8*)(lds + CB + 16384 + bbase + ks[kk]);
    __builtin_amdgcn_global_load_lds(GAS(pB1 + kA2), LAS(lds + CB + 32768 + tid * 16), 16, 0, 0);
    __builtin_amdgcn_global_load_lds(GAS(pB2 + kA2), LAS(lds + CB + 40960 + tid * 16), 16, 0, 0);
    BARR();
    WAITL(); SCHED0();
    __builtin_amdgcn_s_setprio(1);
    #pragma unroll
    for (int kk = 0; kk < 4; ++kk)
        #pragma unroll
        for (int mf = 0; mf < 2; ++mf)
            acc[mf][1] = MFMA32(a[mf][kk], b1[kk], acc[mf][1]);
    __builtin_amdgcn_s_setprio(0);
    SCHED0();

    // ---------- P3 ----------
    #pragma unroll
    for (int mf = 0; mf < 2; ++mf)
        #pragma unroll
        for (int kk = 0; kk < 4; ++kk)
            a[mf][kk] = *(const bf16x8*)(lds + CB + 16384 + abase + mf * 512 + ks[kk]);
    __builtin_amdgcn_global_load_lds(GAS(pB3 + kA2), LAS(lds + CB + 49152 + tid * 16), 16, 0, 0);
    __builtin_amdgcn_global_load_lds(GAS(pB4 + kA2), LAS(lds + CB + 57344 + tid * 16), 16, 0, 0);
    BARR();
    WAITL(); SCHED0();
    __builtin_amdgcn_s_setprio(1);
    #pragma unroll
    for (int kk = 0; kk < 4; ++kk)
        #pragma unroll
        for (int mf = 0; mf < 2; ++mf)
            acc[2 + mf][1] = MFMA32(a[mf][kk], b1[kk], acc[2 + mf][1]);
    __builtin_amdgcn_s_setprio(0);
    SCHED0();

    // ---------- P4 ----------
    __builtin_amdgcn_global_load_lds(GAS(pA1 + kA2), LAS(lds + CB + tid * 16), 16, 0, 0);
    __builtin_amdgcn_global_load_lds(GAS(pA2 + kA2), LAS(lds + CB + 8192 + tid * 16), 16, 0, 0);
    WAITV(6);
    BARR();
    __builtin_amdgcn_s_setprio(1);
    #pragma unroll
    for (int kk = 0; kk < 4; ++kk)
        #pragma unroll
        for (int mf = 0; mf < 2; ++mf)
            acc[2 + mf][0] = MFMA32(a[mf][kk], b0[kk], acc[2 + mf][0]);
    __builtin_amdgcn_s_setprio(0);
    SCHED0();
}

__global__ __launch_bounds__(512, 2) void gemm_kernel(
    const bf16* __restrict__ Ap, const bf16* __restrict__ Wt,
    const bf16* __restrict__ clb, const bf16* __restrict__ srt,
    float* __restrict__ out)
{
    __shared__ uint4 smem[8192]; // 128 KiB
    char* lds = (char*)smem;
    const int tid  = threadIdx.x;
    const int lane = tid & 63;
    const int w    = tid >> 6;
    const int wm   = w >> 2;   // 0..1
    const int wn   = w & 3;    // 0..3
    const int L5 = lane & 31, H1 = lane >> 5;

    // XCD-bijective swizzle, 8x8 tile block per XCD (R7-proven)
    const int bid = blockIdx.x;
    const int xc  = bid & 7, ii = bid >> 3;
    const int mt  = (xc >> 1) * 8 + (ii >> 3);
    const int nt  = (xc & 1) * 8 + (ii & 7);
    const size_t brow = (size_t)mt * 256;
    const size_t bcol = (size_t)nt * 256;

    // staging: dest linear (tid*16) = chunk-major (chunk=tid>>6, row=tid&63);
    // source fetches exactly that element (per-lane scatter, 16B granules)
    const int r6 = tid & 63;
    const int ch = tid >> 6;
    const bf16* pA1 = Ap + (brow + r6) * (size_t)DIN + ch * 8;
    const bf16* pA2 = pA1 + (size_t)64  * DIN;
    const bf16* pA3 = pA1 + (size_t)128 * DIN;
    const bf16* pA4 = pA1 + (size_t)192 * DIN;
    const bf16* pB1 = Wt + (bcol + r6) * (size_t)DIN + ch * 8;
    const bf16* pB2 = pB1 + (size_t)64  * DIN;
    const bf16* pB3 = pB1 + (size_t)128 * DIN;
    const bf16* pB4 = pB1 + (size_t)192 * DIN;

    // fragment read constants: chunk = kk*2 + H1 -> ks[kk] byte offsets;
    // abase/bbase fold sub-call (wm / wn>>1), 32-row half (wn&1), and lane row
    const int ks0 = ((0 * 2 + H1) << 10);
    const int ks1 = ((1 * 2 + H1) << 10);
    const int ks2 = ((2 * 2 + H1) << 10);
    const int ks3 = ((3 * 2 + H1) << 10);
    const int abase = wm * 8192 + L5 * 16;                              // + mf*512
    const int bbase = 32768 + (wn >> 1) * 8192 + (wn & 1) * 512 + L5 * 16;

    bf16x8 a[2][4], b0[4], b1[4];
    f32x16 acc[4][2] = {};

    // prologue staging: tile0 all pieces -> buf0; tile1 {Bh0,Bh1,Ah0} -> buf1
    __builtin_amdgcn_global_load_lds(GAS(pA1), LAS(lds + tid * 16), 16, 0, 0);
    __builtin_amdgcn_global_load_lds(GAS(pA2), LAS(lds + 8192 + tid * 16), 16, 0, 0);
    __builtin_amdgcn_global_load_lds(GAS(pA3), LAS(lds + 16384 + tid * 16), 16, 0, 0);
    __builtin_amdgcn_global_load_lds(GAS(pA4), LAS(lds + 24576 + tid * 16), 16, 0, 0);
    __builtin_amdgcn_global_load_lds(GAS(pB1), LAS(lds + 32768 + tid * 16), 16, 0, 0);
    __builtin_amdgcn_global_load_lds(GAS(pB2), LAS(lds + 40960 + tid * 16), 16, 0, 0);
    __builtin_amdgcn_global_load_lds(GAS(pB3), LAS(lds + 49152 + tid * 16), 16, 0, 0);
    __builtin_amdgcn_global_load_lds(GAS(pB4), LAS(lds + 57344 + tid * 16), 16, 0, 0);
    __builtin_amdgcn_global_load_lds(GAS(pB1 + 64), LAS(lds + 65536 + 32768 + tid * 16), 16, 0, 0);
    __builtin_amdgcn_global_load_lds(GAS(pB2 + 64), LAS(lds + 65536 + 40960 + tid * 16), 16, 0, 0);
    __builtin_amdgcn_global_load_lds(GAS(pB3 + 64), LAS(lds + 65536 + 49152 + tid * 16), 16, 0, 0);
    __builtin_amdgcn_global_load_lds(GAS(pB4 + 64), LAS(lds + 65536 + 57344 + tid * 16), 16, 0, 0);
    __builtin_amdgcn_global_load_lds(GAS(pA1 + 64), LAS(lds + 65536 + tid * 16), 16, 0, 0);
    __builtin_amdgcn_global_load_lds(GAS(pA2 + 64), LAS(lds + 65536 + 8192 + tid * 16), 16, 0, 0);
    WAITV(6);
    BARR();

    #pragma unroll 1
    for (int t = 0; t < 64; t += 2) {
        tile_step<0>(lds, tid, pA1, pA2, pA3, pA4, pB1, pB2, pB3, pB4,
                     ((t + 1) & 63) * 64, ((t + 2) & 63) * 64,
                     abase, bbase, ks0, ks1, ks2, ks3, a, b0, b1, acc);
        tile_step<1>(lds, tid, pA1, pA2, pA3, pA4, pB1, pB2, pB3, pB4,
                     ((t + 2) & 63) * 64, ((t + 3) & 63) * 64,
                     abase, bbase, ks0, ks1, ks2, ks3, a, b0, b1, acc);
    }

    // ---- fused tmpR tile: acc *= (cluster @ style_R) over K=64 ----
    BARR();     // all waves done reading main-loop data before slot reuse
    WAITV(0);   // drain wrap-around junk prefetches
    const bf16* pC = clb + (brow + r6) * 64 + ch * 8;
    const bf16* pR = srt + (bcol + r6) * 64 + ch * 8;
    __builtin_amdgcn_global_load_lds(GAS(pC),            LAS(lds + tid * 16), 16, 0, 0);
    __builtin_amdgcn_global_load_lds(GAS(pC + 64 * 64),  LAS(lds + 8192 + tid * 16), 16, 0, 0);
    __builtin_amdgcn_global_load_lds(GAS(pC + 128 * 64), LAS(lds + 16384 + tid * 16), 16, 0, 0);
    __builtin_amdgcn_global_load_lds(GAS(pC + 192 * 64), LAS(lds + 24576 + tid * 16), 16, 0, 0);
    __builtin_amdgcn_global_load_lds(GAS(pR),            LAS(lds + 32768 + tid * 16), 16, 0, 0);
    __builtin_amdgcn_global_load_lds(GAS(pR + 64 * 64),  LAS(lds + 40960 + tid * 16), 16, 0, 0);
    __builtin_amdgcn_global_load_lds(GAS(pR + 128 * 64), LAS(lds + 49152 + tid * 16), 16, 0, 0);
    __builtin_amdgcn_global_load_lds(GAS(pR + 192 * 64), LAS(lds + 57344 + tid * 16), 16, 0, 0);
    WAITV(0);
    BARR();

    const int ks[4] = {ks0, ks1, ks2, ks3};
    bf16x8 cb[2][4];
    #pragma unroll
    for (int nf = 0; nf < 2; ++nf)
        #pragma unroll
        for (int kk = 0; kk < 4; ++kk)
            cb[nf][kk] = *(const bf16x8*)(lds + 32768 + (nf * 2 + (wn >> 1)) * 8192
                                          + (wn & 1) * 512 + L5 * 16 + ks[kk]);
    #pragma unroll
    for (int mf = 0; mf < 4; ++mf) {
        bf16x8 ca[4];
        #pragma unroll
        for (int kk = 0; kk < 4; ++kk)
            ca[kk] = *(const bf16x8*)(lds + ((mf >> 1) * 2 + wm) * 8192
                                      + (mf & 1) * 512 + L5 * 16 + ks[kk]);
        WAITL(); SCHED0();
        #pragma unroll
        for (int nf = 0; nf < 2; ++nf) {
            f32x16 r = {};
            #pragma unroll
            for (int kk = 0; kk < 4; ++kk)
                r = MFMA32(ca[kk], cb[nf][kk], r);
            acc[mf][nf] *= r;
        }
    }

    // epilogue: out = acc (already modulated)
    // C/D: col=L5, row = (reg&3) + 8*(reg>>2) + 4*H1  [R6-verified]
    #pragma unroll
    for (int mf = 0; mf < 4; ++mf) {
        size_t rbase = brow + (size_t)((mf >> 1) * 128 + wm * 64 + (mf & 1) * 32 + 4 * H1);
        #pragma unroll
        for (int nf = 0; nf < 2; ++nf) {
            size_t col = bcol + (size_t)(nf * 128 + wn * 32 + L5);
            #pragma unroll
            for (int reg = 0; reg < 16; ++reg) {
                size_t row = rbase + (reg & 3) + 8 * (reg >> 2);
                out[row * DOUT + col] = acc[mf][nf][reg];
            }
        }
    }
}

// ---------------------------------------------------------------------------
extern "C" void kernel_launch(void* const* d_in, const int* in_sizes, int n_in,
                              void* d_out, int out_size, void* d_ws, size_t ws_size,
                              hipStream_t stream)
{
    (void)in_sizes; (void)n_in; (void)out_size;
    const float* x  = (const float*)d_in[0];
    const float* cl = (const float*)d_in[1];
    const float* W  = (const float*)d_in[2];
    const float* sL = (const float*)d_in[3];
    const float* sR = (const float*)d_in[4];
    float* out = (float*)d_out;

    // ws: A' (64MiB) | Wt (32MiB) | clb (1MiB) | srt (0.5MiB)
    const size_t AP_BYTES = (size_t)BB * DIN * sizeof(bf16);
    const size_t WT_BYTES = (size_t)DIN * DOUT * sizeof(bf16);
    const size_t CL_BYTES = (size_t)BB * NCL * sizeof(bf16);
    const size_t SR_BYTES = (size_t)DOUT * NCL * sizeof(bf16);
    if (ws_size < AP_BYTES + WT_BYTES + CL_BYTES + SR_BYTES) return;

    char* ws = (char*)d_ws;
    bf16* Ap  = (bf16*)ws;
    bf16* Wt  = (bf16*)(ws + AP_BYTES);
    bf16* clb = (bf16*)(ws + AP_BYTES + WT_BYTES);
    bf16* srt = (bf16*)(ws + AP_BYTES + WT_BYTES + CL_BYTES);

    prologue_kernel<<<dim3(BB / 128, DIN / 128), 256, 0, stream>>>(x, cl, sL, Ap, clb);
    wprep_kernel<<<dim3(2064), 256, 0, stream>>>(W, sR, Wt, srt);
    gemm_kernel<<<dim3((BB / 256) * (DOUT / 256)), 512, 0, stream>>>(Ap, Wt, clb, srt, out);
}

// Round 11
// 300.942 us; speedup vs baseline: 1.2450x; 1.2450x over previous
//
#include <hip/hip_runtime.h>
#include <cstdint>

// Problem constants (from reference): B=8192, DIN=DOUT=4096, NC=64
#define BB   8192
#define DIN  4096
#define DOUT 4096
#define NCL  64

typedef __bf16 bf16;
typedef __attribute__((ext_vector_type(8))) __bf16 bf16x8;
typedef __attribute__((ext_vector_type(4))) float   f32x4;

#define GAS(p) (reinterpret_cast<uint32_t __attribute__((address_space(1)))*>(reinterpret_cast<uintptr_t>(p)))
#define LAS(p) (reinterpret_cast<uint32_t __attribute__((address_space(3)))*>(reinterpret_cast<uintptr_t>(p)))

#define WAITV(n)  asm volatile("s_waitcnt vmcnt(" #n ")" ::: "memory")
#define WAITL()   asm volatile("s_waitcnt lgkmcnt(0)" ::: "memory")
#define BARR()    __builtin_amdgcn_s_barrier()
#define SCHED0()  __builtin_amdgcn_sched_barrier(0)
#define MFMA(a, b, c) __builtin_amdgcn_mfma_f32_16x16x32_bf16((a), (b), (c), 0, 0, 0)

// ---------------------------------------------------------------------------
// Kernel 1: prologue (R7-proven). tmpL = cluster @ style_L (K=64 MFMA);
// A' = bf16(x*tmpL) written via LDS bounce for fully-coalesced x/Ap streams.
// blockIdx.y==0 blocks also dump the cluster tile as bf16 for the GEMM.
// ---------------------------------------------------------------------------
__global__ __launch_bounds__(256) void prologue_kernel(
    const float* __restrict__ x, const float* __restrict__ cl,
    const float* __restrict__ sL, bf16* __restrict__ Ap,
    bf16* __restrict__ clb)
{
    __shared__ char lds[34816]; // 32KB staging, then reused as 128x136 bf16 bounce
    const int t    = threadIdx.x;
    const int lane = t & 63;
    const int w    = t >> 6;
    const int wm   = w >> 1, wn = w & 1;
    const int r0   = blockIdx.x * 128;
    const int c0   = blockIdx.y * 128;

    // stage cluster tile (128x64 f32 -> bf16), swizzled
    #pragma unroll
    for (int i = 0; i < 4; i++) {
        int tk  = t + i * 256;
        int row = tk >> 3, ch = tk & 7;
        const float* src = cl + (size_t)(r0 + row) * NCL + ch * 8;
        float4 v0 = *(const float4*)src;
        float4 v1 = *(const float4*)(src + 4);
        bf16x8 pk;
        pk[0]=(bf16)v0.x; pk[1]=(bf16)v0.y; pk[2]=(bf16)v0.z; pk[3]=(bf16)v0.w;
        pk[4]=(bf16)v1.x; pk[5]=(bf16)v1.y; pk[6]=(bf16)v1.z; pk[7]=(bf16)v1.w;
        *(bf16x8*)(lds + row * 128 + ((ch ^ (row & 7)) << 4)) = pk;
        if (blockIdx.y == 0)
            *(bf16x8*)(clb + (size_t)(r0 + row) * NCL + ch * 8) = pk;
    }
    // stage style_L tile transposed: SL[n][k] = style_L[k][c0+n]
    #pragma unroll
    for (int i = 0; i < 4; i++) {
        int tk = t + i * 256;
        int n  = tk & 127, c = tk >> 7;
        bf16x8 pl;
        #pragma unroll
        for (int j = 0; j < 8; j++)
            pl[j] = (bf16)sL[(size_t)(c * 8 + j) * DIN + c0 + n];
        *(bf16x8*)(lds + 16384 + n * 128 + ((c ^ (n & 7)) << 4)) = pl;
    }
    __syncthreads();

    f32x4 accL[4][4] = {};
    #pragma unroll
    for (int s = 0; s < 2; s++) {
        bf16x8 a[4], bl[4];
        #pragma unroll
        for (int m = 0; m < 4; m++) {
            int row = wm * 64 + m * 16 + (lane & 15);
            int ch  = s * 4 + (lane >> 4);
            a[m] = *(bf16x8*)(lds + row * 128 + ((ch ^ (row & 7)) << 4));
        }
        #pragma unroll
        for (int n = 0; n < 4; n++) {
            int row = wn * 64 + n * 16 + (lane & 15);
            int ch  = s * 4 + (lane >> 4);
            bl[n] = *(bf16x8*)(lds + 16384 + row * 128 + ((ch ^ (row & 7)) << 4));
        }
        #pragma unroll
        for (int m = 0; m < 4; m++)
            #pragma unroll
            for (int n = 0; n < 4; n++)
                accL[m][n] = MFMA(a[m], bl[n], accL[m][n]);
    }
    __syncthreads();   // staging LDS dead; reuse as bounce buffer

    // scatter tmpL (bf16) -> LDS [128 rows][136 cols]
    #pragma unroll
    for (int m = 0; m < 4; m++) {
        int rbase = wm * 64 + m * 16 + ((lane >> 4) << 2);
        #pragma unroll
        for (int n = 0; n < 4; n++) {
            int col = wn * 64 + n * 16 + (lane & 15);
            #pragma unroll
            for (int j = 0; j < 4; j++)
                *(bf16*)(lds + (rbase + j) * 272 + col * 2) = (bf16)accL[m][n][j];
        }
    }
    __syncthreads();

    // coalesced pass: Ap = bf16(x * tmpL); quarter-wave = one row, 512B x-read
    const int L = t & 15, H = (t >> 4) & 3;
    #pragma unroll
    for (int it = 0; it < 8; it++) {
        int row = it * 16 + w * 4 + H;
        bf16x8 tl = *(const bf16x8*)(lds + row * 272 + L * 16);
        const float* xs = x + (size_t)(r0 + row) * DIN + c0 + L * 8;
        float4 x0 = *(const float4*)xs;
        float4 x1 = *(const float4*)(xs + 4);
        bf16x8 o;
        o[0]=(bf16)(x0.x*(float)tl[0]); o[1]=(bf16)(x0.y*(float)tl[1]);
        o[2]=(bf16)(x0.z*(float)tl[2]); o[3]=(bf16)(x0.w*(float)tl[3]);
        o[4]=(bf16)(x1.x*(float)tl[4]); o[5]=(bf16)(x1.y*(float)tl[5]);
        o[6]=(bf16)(x1.z*(float)tl[6]); o[7]=(bf16)(x1.w*(float)tl[7]);
        *(bf16x8*)(Ap + (size_t)(r0 + row) * DIN + c0 + L * 8) = o;
    }
}

// ---------------------------------------------------------------------------
// Kernel 2 (fused streaming prep): block-range dispatch, no LDS, low regs.
//   blocks [0,2048):    W (DIN x DOUT f32) -> Wt (DOUT x DIN bf16)
//   blocks [2048,2064): style_R (64 x DOUT f32) -> sRt (DOUT x 64 bf16)
// ---------------------------------------------------------------------------
__global__ __launch_bounds__(256) void wprep_kernel(
    const float* __restrict__ W, const float* __restrict__ sR,
    bf16* __restrict__ Wt, bf16* __restrict__ srt)
{
    const int bid = blockIdx.x;
    const int t   = threadIdx.x;
    if (bid < 2048) {
        const int n  = (bid & 15) * 256 + t;
        const int k0 = (bid >> 4) * 32;
        bf16x8 v[4];
        #pragma unroll
        for (int q = 0; q < 4; q++)
            #pragma unroll
            for (int j = 0; j < 8; j++)
                v[q][j] = (bf16)W[(size_t)(k0 + q * 8 + j) * DOUT + n];
        bf16* dst = Wt + (size_t)n * DIN + k0;
        #pragma unroll
        for (int q = 0; q < 4; q++)
            *(bf16x8*)(dst + q * 8) = v[q];
    } else {
        const int o = (bid - 2048) * 256 + t;
        bf16x8 v[8];
        #pragma unroll
        for (int q = 0; q < 8; q++)
            #pragma unroll
            for (int j = 0; j < 8; j++)
                v[q][j] = (bf16)sR[(size_t)(q * 8 + j) * DOUT + o];
        bf16* dst = srt + (size_t)o * 64;
        #pragma unroll
        for (int q = 0; q < 8; q++)
            *(bf16x8*)(dst + q * 8) = v[q];
    }
}

// ---------------------------------------------------------------------------
// Kernel 3: 256x256-tile GEMM, 16x16x32 MFMA, 4 barriers/K-tile (R9-proven).
// Each phase: {ds_reads; stage; [P4: vmcnt(6)]; BAR; lgkm0; MFMA; sched0}.
// Read balance 12/4/8/0, fused tmpR, XCD 8x8 mapping, 0 bank conflicts.
// ---------------------------------------------------------------------------
template<int CUR>
__device__ __forceinline__ void tile_step(char* lds, int tid,
    const bf16* pA1, const bf16* pA2, const bf16* pA3, const bf16* pA4,
    const bf16* pB1, const bf16* pB2, const bf16* pB3, const bf16* pB4,
    int kA1, int kA2, int aoff0, int aoff1, int boff0, int boff1,
    bf16x8 a[4][2], bf16x8 b[4][2], f32x4 acc[8][4])
{
    constexpr int CB = CUR * 65536;
    constexpr int OB = (CUR ^ 1) * 65536;

    // ---------- P1 ----------
    #pragma unroll
    for (int mq = 0; mq < 4; ++mq) {
        a[mq][0] = *(const bf16x8*)(lds + CB + mq * 2048 + aoff0);
        a[mq][1] = *(const bf16x8*)(lds + CB + mq * 2048 + aoff1);
    }
    #pragma unroll
    for (int nb = 0; nb < 2; ++nb) {
        b[nb][0] = *(const bf16x8*)(lds + CB + nb * 2048 + boff0);
        b[nb][1] = *(const bf16x8*)(lds + CB + nb * 2048 + boff1);
    }
    __builtin_amdgcn_global_load_lds(GAS(pA3 + kA1), LAS(lds + OB + 16384 + tid * 16), 16, 0, 0);
    __builtin_amdgcn_global_load_lds(GAS(pA4 + kA1), LAS(lds + OB + 24576 + tid * 16), 16, 0, 0);
    BARR();
    WAITL(); SCHED0();
    __builtin_amdgcn_s_setprio(1);
    #pragma unroll
    for (int k = 0; k < 2; ++k)
        #pragma unroll
        for (int mq = 0; mq < 4; ++mq)
            #pragma unroll
            for (int nq = 0; nq < 2; ++nq)
                acc[mq][nq] = MFMA(a[mq][k], b[nq][k], acc[mq][nq]);
    __builtin_amdgcn_s_setprio(0);
    SCHED0();

    // ---------- P2 ----------
    #pragma unroll
    for (int nb = 2; nb < 4; ++nb) {
        b[nb][0] = *(const bf16x8*)(lds + CB + nb * 2048 + boff0);
        b[nb][1] = *(const bf16x8*)(lds + CB + nb * 2048 + boff1);
    }
    __builtin_amdgcn_global_load_lds(GAS(pB1 + kA2), LAS(lds + CB + 32768 + tid * 16), 16, 0, 0);
    __builtin_amdgcn_global_load_lds(GAS(pB2 + kA2), LAS(lds + CB + 40960 + tid * 16), 16, 0, 0);
    BARR();
    WAITL(); SCHED0();
    __builtin_amdgcn_s_setprio(1);
    #pragma unroll
    for (int k = 0; k < 2; ++k)
        #pragma unroll
        for (int mq = 0; mq < 4; ++mq)
            #pragma unroll
            for (int nq = 0; nq < 2; ++nq)
                acc[mq][2 + nq] = MFMA(a[mq][k], b[2 + nq][k], acc[mq][2 + nq]);
    __builtin_amdgcn_s_setprio(0);
    SCHED0();

    // ---------- P3 ----------
    #pragma unroll
    for (int mq = 0; mq < 4; ++mq) {
        a[mq][0] = *(const bf16x8*)(lds + CB + 8192 + mq * 2048 + aoff0);
        a[mq][1] = *(const bf16x8*)(lds + CB + 8192 + mq * 2048 + aoff1);
    }
    __builtin_amdgcn_global_load_lds(GAS(pB3 + kA2), LAS(lds + CB + 49152 + tid * 16), 16, 0, 0);
    __builtin_amdgcn_global_load_lds(GAS(pB4 + kA2), LAS(lds + CB + 57344 + tid * 16), 16, 0, 0);
    BARR();
    WAITL(); SCHED0();
    __builtin_amdgcn_s_setprio(1);
    #pragma unroll
    for (int k = 0; k < 2; ++k)
        #pragma unroll
        for (int mq = 0; mq < 4; ++mq)
            #pragma unroll
            for (int nq = 0; nq < 2; ++nq)
                acc[4 + mq][2 + nq] = MFMA(a[mq][k], b[2 + nq][k], acc[4 + mq][2 + nq]);
    __builtin_amdgcn_s_setprio(0);
    SCHED0();

    // ---------- P4 ----------
    __builtin_amdgcn_global_load_lds(GAS(pA1 + kA2), LAS(lds + CB + tid * 16), 16, 0, 0);
    __builtin_amdgcn_global_load_lds(GAS(pA2 + kA2), LAS(lds + CB + 8192 + tid * 16), 16, 0, 0);
    WAITV(6);
    BARR();
    __builtin_amdgcn_s_setprio(1);
    #pragma unroll
    for (int k = 0; k < 2; ++k)
        #pragma unroll
        for (int mq = 0; mq < 4; ++mq)
            #pragma unroll
            for (int nq = 0; nq < 2; ++nq)
                acc[4 + mq][nq] = MFMA(a[mq][k], b[nq][k], acc[4 + mq][nq]);
    __builtin_amdgcn_s_setprio(0);
    SCHED0();
}

__global__ __launch_bounds__(512, 2) void gemm_kernel(
    const bf16* __restrict__ Ap, const bf16* __restrict__ Wt,
    const bf16* __restrict__ clb, const bf16* __restrict__ srt,
    float* __restrict__ out)
{
    __shared__ uint4 smem[8192]; // 128 KiB
    char* lds = (char*)smem;
    const int tid  = threadIdx.x;
    const int lane = tid & 63;
    const int w    = tid >> 6;
    const int wm   = w >> 2;   // 0..1
    const int wn   = w & 3;    // 0..3
    const int L = lane & 15, H = lane >> 4;

    // XCD-bijective swizzle, 8x8 tile block per XCD
    const int bid = blockIdx.x;
    const int xc  = bid & 7, ii = bid >> 3;
    const int mt  = (xc >> 1) * 8 + (ii >> 3);
    const int nt  = (xc & 1) * 8 + (ii & 7);
    const size_t brow = (size_t)mt * 256;
    const size_t bcol = (size_t)nt * 256;

    // staging: dest linear (tid*16), source chunk inverse-swizzled
    const int r1  = tid >> 3;
    const int gch = (tid & 7) ^ (r1 & 7);
    const bf16* pA1 = Ap + (brow + r1) * (size_t)DIN + gch * 8;
    const bf16* pA2 = pA1 + (size_t)64  * DIN;
    const bf16* pA3 = pA1 + (size_t)128 * DIN;
    const bf16* pA4 = pA1 + (size_t)192 * DIN;
    const bf16* pB1 = Wt + (bcol + r1) * (size_t)DIN + gch * 8;
    const bf16* pB2 = pB1 + (size_t)64  * DIN;
    const bf16* pB3 = pB1 + (size_t)128 * DIN;
    const bf16* pB4 = pB1 + (size_t)192 * DIN;

    // fragment ds_read offsets: chunk = kk*4+H, slot = chunk^(L&7)
    const int swz0 = (H ^ (L & 7)) << 4;
    const int swz1 = ((4 + H) ^ (L & 7)) << 4;
    const int aoff0 = wm * 16384 + L * 128 + swz0;
    const int aoff1 = wm * 16384 + L * 128 + swz1;
    const int boff0 = 32768 + (wn >> 1) * 16384 + (wn & 1) * 8192 + L * 128 + swz0;
    const int boff1 = 32768 + (wn >> 1) * 16384 + (wn & 1) * 8192 + L * 128 + swz1;

    bf16x8 a[4][2], b[4][2];
    f32x4 acc[8][4] = {};

    // prologue: tile0 all 4 pieces -> buf0; tile1 {Bh0,Bh1,Ah0} -> buf1
    __builtin_amdgcn_global_load_lds(GAS(pA1), LAS(lds + tid * 16), 16, 0, 0);
    __builtin_amdgcn_global_load_lds(GAS(pA2), LAS(lds + 8192 + tid * 16), 16, 0, 0);
    __builtin_amdgcn_global_load_lds(GAS(pA3), LAS(lds + 16384 + tid * 16), 16, 0, 0);
    __builtin_amdgcn_global_load_lds(GAS(pA4), LAS(lds + 24576 + tid * 16), 16, 0, 0);
    __builtin_amdgcn_global_load_lds(GAS(pB1), LAS(lds + 32768 + tid * 16), 16, 0, 0);
    __builtin_amdgcn_global_load_lds(GAS(pB2), LAS(lds + 40960 + tid * 16), 16, 0, 0);
    __builtin_amdgcn_global_load_lds(GAS(pB3), LAS(lds + 49152 + tid * 16), 16, 0, 0);
    __builtin_amdgcn_global_load_lds(GAS(pB4), LAS(lds + 57344 + tid * 16), 16, 0, 0);
    __builtin_amdgcn_global_load_lds(GAS(pB1 + 64), LAS(lds + 65536 + 32768 + tid * 16), 16, 0, 0);
    __builtin_amdgcn_global_load_lds(GAS(pB2 + 64), LAS(lds + 65536 + 40960 + tid * 16), 16, 0, 0);
    __builtin_amdgcn_global_load_lds(GAS(pB3 + 64), LAS(lds + 65536 + 49152 + tid * 16), 16, 0, 0);
    __builtin_amdgcn_global_load_lds(GAS(pB4 + 64), LAS(lds + 65536 + 57344 + tid * 16), 16, 0, 0);
    __builtin_amdgcn_global_load_lds(GAS(pA1 + 64), LAS(lds + 65536 + tid * 16), 16, 0, 0);
    __builtin_amdgcn_global_load_lds(GAS(pA2 + 64), LAS(lds + 65536 + 8192 + tid * 16), 16, 0, 0);
    WAITV(6);
    BARR();

    #pragma unroll 1
    for (int t = 0; t < 64; t += 2) {
        tile_step<0>(lds, tid, pA1, pA2, pA3, pA4, pB1, pB2, pB3, pB4,
                     ((t + 1) & 63) * 64, ((t + 2) & 63) * 64,
                     aoff0, aoff1, boff0, boff1, a, b, acc);
        tile_step<1>(lds, tid, pA1, pA2, pA3, pA4, pB1, pB2, pB3, pB4,
                     ((t + 2) & 63) * 64, ((t + 3) & 63) * 64,
                     aoff0, aoff1, boff0, boff1, a, b, acc);
    }

    // ---- fused tmpR tile: acc *= (cluster @ style_R) over K=64 ----
    BARR();     // all waves done reading main-loop data before slot reuse
    WAITV(0);   // drain wrap-around junk prefetches BEFORE reusing their LDS slots
    const bf16* pC = clb + (brow + r1) * 64 + gch * 8;
    const bf16* pR = srt + (bcol + r1) * 64 + gch * 8;
    __builtin_amdgcn_global_load_lds(GAS(pC),         LAS(lds + tid * 16), 16, 0, 0);
    __builtin_amdgcn_global_load_lds(GAS(pC + 4096),  LAS(lds + 8192 + tid * 16), 16, 0, 0);
    __builtin_amdgcn_global_load_lds(GAS(pC + 8192),  LAS(lds + 16384 + tid * 16), 16, 0, 0);
    __builtin_amdgcn_global_load_lds(GAS(pC + 12288), LAS(lds + 24576 + tid * 16), 16, 0, 0);
    __builtin_amdgcn_global_load_lds(GAS(pR),         LAS(lds + 32768 + tid * 16), 16, 0, 0);
    __builtin_amdgcn_global_load_lds(GAS(pR + 4096),  LAS(lds + 40960 + tid * 16), 16, 0, 0);
    __builtin_amdgcn_global_load_lds(GAS(pR + 8192),  LAS(lds + 49152 + tid * 16), 16, 0, 0);
    __builtin_amdgcn_global_load_lds(GAS(pR + 12288), LAS(lds + 57344 + tid * 16), 16, 0, 0);
    WAITV(0);
    BARR();

    #pragma unroll
    for (int nb = 0; nb < 4; ++nb) {
        b[nb][0] = *(const bf16x8*)(lds + nb * 2048 + boff0);
        b[nb][1] = *(const bf16x8*)(lds + nb * 2048 + boff1);
    }
    #pragma unroll
    for (int half = 0; half < 2; ++half) {
        #pragma unroll
        for (int mq = 0; mq < 4; ++mq) {
            a[mq][0] = *(const bf16x8*)(lds + half * 8192 + mq * 2048 + aoff0);
            a[mq][1] = *(const bf16x8*)(lds + half * 8192 + mq * 2048 + aoff1);
        }
        WAITL(); SCHED0();
        f32x4 r4[4][4] = {};
        #pragma unroll
        for (int k = 0; k < 2; ++k)
            #pragma unroll
            for (int mq = 0; mq < 4; ++mq)
                #pragma unroll
                for (int nb = 0; nb < 4; ++nb)
                    r4[mq][nb] = MFMA(a[mq][k], b[nb][k], r4[mq][nb]);
        #pragma unroll
        for (int mq = 0; mq < 4; ++mq)
            #pragma unroll
            for (int nb = 0; nb < 4; ++nb)
                acc[half * 4 + mq][nb] *= r4[mq][nb];
    }

    // epilogue: out = acc (already modulated), f32 stores
    #pragma unroll
    for (int m = 0; m < 8; m++) {
        size_t rbase = brow + (size_t)(wm * 128 + m * 16 + (H << 2));
        #pragma unroll
        for (int n = 0; n < 4; n++) {
            size_t col = bcol + (size_t)(wn * 64 + n * 16 + L);
            #pragma unroll
            for (int j = 0; j < 4; j++) {
                size_t idx = (rbase + j) * DOUT + col;
                out[idx] = acc[m][n][j];
            }
        }
    }
}

// ---------------------------------------------------------------------------
extern "C" void kernel_launch(void* const* d_in, const int* in_sizes, int n_in,
                              void* d_out, int out_size, void* d_ws, size_t ws_size,
                              hipStream_t stream)
{
    (void)in_sizes; (void)n_in; (void)out_size;
    const float* x  = (const float*)d_in[0];
    const float* cl = (const float*)d_in[1];
    const float* W  = (const float*)d_in[2];
    const float* sL = (const float*)d_in[3];
    const float* sR = (const float*)d_in[4];
    float* out = (float*)d_out;

    // ws: A' (64MiB) | Wt (32MiB) | clb (1MiB) | srt (0.5MiB)
    const size_t AP_BYTES = (size_t)BB * DIN * sizeof(bf16);
    const size_t WT_BYTES = (size_t)DIN * DOUT * sizeof(bf16);
    const size_t CL_BYTES = (size_t)BB * NCL * sizeof(bf16);
    const size_t SR_BYTES = (size_t)DOUT * NCL * sizeof(bf16);
    if (ws_size < AP_BYTES + WT_BYTES + CL_BYTES + SR_BYTES) return;

    char* ws = (char*)d_ws;
    bf16* Ap  = (bf16*)ws;
    bf16* Wt  = (bf16*)(ws + AP_BYTES);
    bf16* clb = (bf16*)(ws + AP_BYTES + WT_BYTES);
    bf16* srt = (bf16*)(ws + AP_BYTES + WT_BYTES + CL_BYTES);

    prologue_kernel<<<dim3(BB / 128, DIN / 128), 256, 0, stream>>>(x, cl, sL, Ap, clb);
    wprep_kernel<<<dim3(2064), 256, 0, stream>>>(W, sR, Wt, srt);
    gemm_kernel<<<dim3((BB / 256) * (DOUT / 256)), 512, 0, stream>>>(Ap, Wt, clb, srt, out);
}